// Round 12
// baseline (433.027 us; speedup 1.0000x reference)
//
#include <hip/hip_runtime.h>
#include <math.h>

#define D_DIM 128
#define H_DIM 256
#define W_DIM 256
#define HW (H_DIM * W_DIM)
#define HW4 (HW / 4)
#define NIMG 2
#define NPI (D_DIM * HW)
#define NTOT (NIMG * NPI)

#define TDZ 8
#define TH 16
#define TW 64

#define AW4 18   // aS chunks/row: chunk c -> gx = x0-4+4c  (x0-4 .. x0+67)
#define AH 20    // aS rows: gy = y0-2 .. y0+17
#define EW4 17   // eT chunks/row: chunk c -> gx = x0-2+4c  (x0-2 .. x0+65)
#define EH 18    // eT rows: gy = y0-1 .. y0+16

#define NLOAD (AH * AW4)      // 360 real items
#define NLOADP 384            // padded to 6 full waves
#define NERO  (EH * EW4)      // 306
#define NOUT  (TH * (TW/4))   // 256

#define NUM_ITER 20
#define STOP_THRESH 1e-4

__device__ __forceinline__ float min3f(float a, float b, float c) { return fminf(fminf(a, b), c); }
__device__ __forceinline__ float max3f(float a, float b, float c) { return fmaxf(fmaxf(a, b), c); }
__device__ __forceinline__ float leaky(float x) { return fmaxf(x, 0.01f * x); }

// B1 variants: drain gloads but leave prior-iter stores in flight where safe.
#define BAR_FULL() do { asm volatile("s_waitcnt vmcnt(0) lgkmcnt(0)" ::: "memory"); \
                        __builtin_amdgcn_s_barrier(); \
                        __builtin_amdgcn_sched_barrier(0); } while (0)
#define BAR_VM2()  do { asm volatile("s_waitcnt vmcnt(2) lgkmcnt(0)" ::: "memory"); \
                        __builtin_amdgcn_s_barrier(); \
                        __builtin_amdgcn_sched_barrier(0); } while (0)
#define BAR_VM1()  do { asm volatile("s_waitcnt vmcnt(1) lgkmcnt(0)" ::: "memory"); \
                        __builtin_amdgcn_s_barrier(); \
                        __builtin_amdgcn_sched_barrier(0); } while (0)
// B2: LDS-only drain — keeps global_load_lds for slice i+1 in flight
#define BAR_LDS() do { asm volatile("s_waitcnt lgkmcnt(0)" ::: "memory"); \
                       __builtin_amdgcn_s_barrier(); \
                       __builtin_amdgcn_sched_barrier(0); } while (0)

#define GLOAD_LDS(gp, lp) \
    __builtin_amdgcn_global_load_lds((const __attribute__((address_space(1))) unsigned int*)(gp), \
                                     (__attribute__((address_space(3))) unsigned int*)(lp), 16, 0, 0)

__global__ void init_slots(double* slots) {
    int t = threadIdx.x;
    if (t < 32) slots[t] = 0.0;
    if (t >= 32 && t < 36) ((float*)(slots + 32))[t - 32] = INFINITY;  // 16B +INF cell
}

// R11 structure, TDZ 16->8: grid 2048 blocks = 8 blocks/CU for TLP.
// Tile 64x16x8, all 256 threads active in every stage.
__global__ __launch_bounds__(256) void skel_step(
    const float* __restrict__ a_in,
    float* __restrict__ a_out,
    float* __restrict__ skel,
    double* __restrict__ slots,
    int step)
{
    __shared__ float4 aS4[2][NLOADP];  // 12288 B (ping-pong, lds-load dest)
    __shared__ float4 eT4[NERO];       // 4896 B
    __shared__ float wsum[4];
    __shared__ int s_active;

    const int t = threadIdx.x;

    if (t == 0) {
        int act = 1;
        for (int j = 1; j < step; ++j)
            if (!(slots[j] >= STOP_THRESH * (double)NTOT)) { act = 0; break; }
        s_active = act;
    }
    __syncthreads();
    if (!s_active) return;

    const float* infp = (const float*)(slots + 32);

    // XCD-aware swizzle: grid (4,16,32) = 2048 blocks; XCD k owns swz in
    // [256k, 256(k+1)) = full xy coverage of 4 adjacent z-slabs.
    const int lid = blockIdx.x + 4 * (blockIdx.y + 16 * blockIdx.z);
    const int swz = (lid & 7) * 256 + (lid >> 3);
    const int bx = swz & 3;
    const int by = (swz >> 2) & 15;
    const int zz = swz >> 6;           // 0..31
    const int bz = zz & 15, img = zz >> 4;
    const int x0 = bx * TW, y0 = by * TH, z0 = bz * TDZ;

    const float* in = a_in + (size_t)img * NPI;
    float4* aout4 = (float4*)(a_out + (size_t)img * NPI);
    float4* sk4 = (float4*)(skel + (size_t)img * NPI);

    // ---- load items: q0 = t (all), q1 = 256+t (t<128; q1>=360 -> pad/INF) ----
    int lOff0; bool lVal0;
    {
        int lr = t / AW4, lc = t - lr * AW4;
        int gy = y0 - 2 + lr, gx = x0 - 4 + 4 * lc;
        lVal0 = ((unsigned)gy < H_DIM) && ((unsigned)gx <= (unsigned)(W_DIM - 4));
        lOff0 = gy * W_DIM + gx;
    }
    const bool hasL1 = t < 128;          // wave-uniform
    int lOff1 = 0; bool lVal1 = false;
    if (hasL1) {
        int q = t + 256;
        int lr = q / AW4, lc = q - lr * AW4;
        int gy = y0 - 2 + lr, gx = x0 - 4 + 4 * lc;
        lVal1 = (q < NLOAD) && ((unsigned)gy < H_DIM) && ((unsigned)gx <= (unsigned)(W_DIM - 4));
        lOff1 = gy * W_DIM + gx;
    }
    const int wbase = (t >> 6) << 6;     // wave-uniform LDS base (element units)

    // ---- erode items ----
    int eRd0; bool sA0, sB0, sC0, sD0;
    {
        int mh = t / EW4, ej = t - mh * EW4;
        eRd0 = mh * AW4 + ej;
        int gy = y0 - 1 + mh;
        bool gok = (unsigned)gy < H_DIM;
        int gxb = x0 - 2 + 4 * ej;
        sA0 = gok && ((unsigned)(gxb + 0) < W_DIM);
        sB0 = gok && ((unsigned)(gxb + 1) < W_DIM);
        sC0 = gok && ((unsigned)(gxb + 2) < W_DIM);
        sD0 = gok && ((unsigned)(gxb + 3) < W_DIM);
    }
    const bool hasE1 = t < (NERO - 256);    // t < 50
    int eRd1 = 0; bool sA1 = false, sB1 = false, sC1 = false, sD1 = false;
    if (hasE1) {
        int q = t + 256;
        int mh = q / EW4, ej = q - mh * EW4;
        eRd1 = mh * AW4 + ej;
        int gy = y0 - 1 + mh;
        bool gok = (unsigned)gy < H_DIM;
        int gxb = x0 - 2 + 4 * ej;
        sA1 = gok && ((unsigned)(gxb + 0) < W_DIM);
        sB1 = gok && ((unsigned)(gxb + 1) < W_DIM);
        sC1 = gok && ((unsigned)(gxb + 2) < W_DIM);
        sD1 = gok && ((unsigned)(gxb + 3) < W_DIM);
    }

    // ---- out item ----
    const int oh = t >> 4, wq = t & 15;
    const int oRd = oh * EW4 + wq;
    const int oAc = (oh + 2) * AW4 + wq + 1;
    size_t ob = ((size_t)z0 * HW + (size_t)(y0 + oh) * W_DIM + (size_t)x0) / 4 + wq;

    const float INF = INFINITY;
    const float4 inf4 = make_float4(INF, INF, INF, INF);
    const float4 ninf4 = make_float4(-INF, -INF, -INF, -INF);
    float4 m0P2 = inf4, m0P1 = inf4, m1P2 = inf4, m1P1 = inf4;
    float4 xP2 = ninf4, xP1 = ninf4;
    float4 acA = make_float4(0, 0, 0, 0), acB = acA, ecA = acA;
    float lsum = 0.f;

    // ---- prologue: issue slice 0 (z = z0-2) into aS4[0] ----
    {
        int z = z0 - 2;
        bool zok = (unsigned)z < D_DIM;
        const float* p = in + (size_t)z * HW;
        const float* s0 = (zok && lVal0) ? (p + lOff0) : infp;
        GLOAD_LDS(s0, &aS4[0][wbase]);
        if (hasL1) {
            const float* s1 = (zok && lVal1) ? (p + lOff1) : infp;
            GLOAD_LDS(s1, &aS4[0][256 + wbase]);
        }
    }

    for (int i = 0; i < TDZ + 4; ++i) {
        const int cur = i & 1;

        // B1: aS4[cur] loaded. i<5: nothing but gloads outstanding -> full
        // drain. i>=5: leave prior-iter stores (2; 1 at step 20) in flight.
        if (i < 5) { BAR_FULL(); }
        else if (step == NUM_ITER) { BAR_VM1(); }
        else { BAR_VM2(); }

        // early skel prefetch for this iteration's output
        float4 ggPre;
        if (step > 0 && i >= 4) ggPre = sk4[ob];

        // issue slice i+1 into aS4[cur^1] (stays in flight across B2)
        if (i <= TDZ + 2) {
            int z = z0 - 1 + i;
            bool zok = (unsigned)z < D_DIM;
            const float* p = in + (size_t)z * HW;
            const float* s0 = (zok && lVal0) ? (p + lOff0) : infp;
            GLOAD_LDS(s0, &aS4[cur ^ 1][wbase]);
            if (hasL1) {
                const float* s1 = (zok && lVal1) ? (p + lOff1) : infp;
                GLOAD_LDS(s1, &aS4[cur ^ 1][256 + wbase]);
            }
        }

        const bool zp = (unsigned)(z0 - 3 + i) < D_DIM;   // erosion slice in volume?

        // ---- erode: a-slices (i-2,i-1,i) -> erosion z0-3+i -> eT4 ----
        {
            const float4* s = aS4[cur];
            float4 a0 = s[eRd0],           b0 = s[eRd0 + 1];
            float4 a1 = s[eRd0 + AW4],     b1 = s[eRd0 + AW4 + 1];
            float4 a2 = s[eRd0 + 2 * AW4], b2 = s[eRd0 + 2 * AW4 + 1];
            float4 va, vb, mC;
            va.x = min3f(a0.x, a1.x, a2.x);
            va.y = min3f(a0.y, a1.y, a2.y);
            va.z = min3f(a0.z, a1.z, a2.z);
            va.w = min3f(a0.w, a1.w, a2.w);
            vb.x = min3f(b0.x, b1.x, b2.x);
            vb.y = min3f(b0.y, b1.y, b2.y);
            vb.z = min3f(b0.z, b1.z, b2.z);
            mC.x = min3f(va.y, va.z, va.w);
            mC.y = min3f(va.z, va.w, vb.x);
            mC.z = min3f(va.w, vb.x, vb.y);
            mC.w = min3f(vb.x, vb.y, vb.z);
            if (i >= 2 && zp) {
                float4 e;
                e.x = sA0 ? min3f(m0P2.x, m0P1.x, mC.x) : -INF;
                e.y = sB0 ? min3f(m0P2.y, m0P1.y, mC.y) : -INF;
                e.z = sC0 ? min3f(m0P2.z, m0P1.z, mC.z) : -INF;
                e.w = sD0 ? min3f(m0P2.w, m0P1.w, mC.w) : -INF;
                eT4[t] = e;
            }
            m0P2 = m0P1; m0P1 = mC;
        }
        if (hasE1) {
            const float4* s = aS4[cur];
            float4 a0 = s[eRd1],           b0 = s[eRd1 + 1];
            float4 a1 = s[eRd1 + AW4],     b1 = s[eRd1 + AW4 + 1];
            float4 a2 = s[eRd1 + 2 * AW4], b2 = s[eRd1 + 2 * AW4 + 1];
            float4 va, vb, mC;
            va.x = min3f(a0.x, a1.x, a2.x);
            va.y = min3f(a0.y, a1.y, a2.y);
            va.z = min3f(a0.z, a1.z, a2.z);
            va.w = min3f(a0.w, a1.w, a2.w);
            vb.x = min3f(b0.x, b1.x, b2.x);
            vb.y = min3f(b0.y, b1.y, b2.y);
            vb.z = min3f(b0.z, b1.z, b2.z);
            mC.x = min3f(va.y, va.z, va.w);
            mC.y = min3f(va.z, va.w, vb.x);
            mC.z = min3f(va.w, vb.x, vb.y);
            mC.w = min3f(vb.x, vb.y, vb.z);
            if (i >= 2 && zp) {
                float4 e;
                e.x = sA1 ? min3f(m1P2.x, m1P1.x, mC.x) : -INF;
                e.y = sB1 ? min3f(m1P2.y, m1P1.y, mC.y) : -INF;
                e.z = sC1 ? min3f(m1P2.z, m1P1.z, mC.z) : -INF;
                e.w = sD1 ? min3f(m1P2.w, m1P1.w, mC.w) : -INF;
                eT4[t + 256] = e;
            }
            m1P2 = m1P1; m1P1 = mC;
        }

        BAR_LDS();  // B2: eT4 ready (vmcnt NOT drained — slice i+1 still in flight)

        // ---- out: dilate erosion slice z0-3+i; output z0-4+i ----
        {
            const float4 aCn = aS4[cur][oAc];
            float4 xC, ecB;
            if (i >= 2 && zp) {
                float4 A0 = eT4[oRd],           B0 = eT4[oRd + 1];
                float4 A1 = eT4[oRd + EW4],     B1 = eT4[oRd + EW4 + 1];
                float4 A2 = eT4[oRd + 2 * EW4], B2 = eT4[oRd + 2 * EW4 + 1];
                float4 va, vb;
                va.x = max3f(A0.x, A1.x, A2.x);
                va.y = max3f(A0.y, A1.y, A2.y);
                va.z = max3f(A0.z, A1.z, A2.z);
                va.w = max3f(A0.w, A1.w, A2.w);
                vb.x = max3f(B0.x, B1.x, B2.x);
                vb.y = max3f(B0.y, B1.y, B2.y);
                vb.z = max3f(B0.z, B1.z, B2.z);
                xC.x = max3f(va.y, va.z, va.w);
                xC.y = max3f(va.z, va.w, vb.x);
                xC.z = max3f(va.w, vb.x, vb.y);
                xC.w = max3f(vb.x, vb.y, vb.z);
                ecB.x = A1.z; ecB.y = A1.w; ecB.z = B1.x; ecB.w = B1.y;
            } else {
                xC = ninf4; ecB = ninf4;
            }

            if (i >= 4) {
                float4 dl;
                dl.x = leaky(acA.x - max3f(xP2.x, xP1.x, xC.x));
                dl.y = leaky(acA.y - max3f(xP2.y, xP1.y, xC.y));
                dl.z = leaky(acA.z - max3f(xP2.z, xP1.z, xC.z));
                dl.w = leaky(acA.w - max3f(xP2.w, xP1.w, xC.w));
                if (step < NUM_ITER) aout4[ob] = ecA;
                if (step == 0) {
                    sk4[ob] = dl;
                } else {
                    float4 gg = ggPre;
                    float4 up, gn;
                    up.x = leaky(dl.x - gg.x * dl.x); gn.x = gg.x + up.x;
                    up.y = leaky(dl.y - gg.y * dl.y); gn.y = gg.y + up.y;
                    up.z = leaky(dl.z - gg.z * dl.z); gn.z = gg.z + up.z;
                    up.w = leaky(dl.w - gg.w * dl.w); gn.w = gg.w + up.w;
                    sk4[ob] = gn;
                    if (step == 1)
                        lsum += fabsf(gn.x) + fabsf(gn.y) + fabsf(gn.z) + fabsf(gn.w);
                    else
                        lsum += fabsf(up.x) + fabsf(up.y) + fabsf(up.z) + fabsf(up.w);
                }
                ob += HW4;
            }
            xP2 = xP1; xP1 = xC;
            acA = acB; acB = aCn;
            ecA = ecB;
        }
    }

    // dn reduction: one double atomic per block
    if (step > 0) {
        #pragma unroll
        for (int off = 32; off > 0; off >>= 1)
            lsum += __shfl_down(lsum, off, 64);
        const int lane = t & 63, wid = t >> 6;
        if (lane == 0) wsum[wid] = lsum;
        __syncthreads();
        if (t == 0) {
            float b = wsum[0] + wsum[1] + wsum[2] + wsum[3];
            atomicAdd(&slots[step], (double)b);
        }
    }
}

extern "C" void kernel_launch(void* const* d_in, const int* in_sizes, int n_in,
                              void* d_out, int out_size, void* d_ws, size_t ws_size,
                              hipStream_t stream) {
    const float* img = (const float*)d_in[0];
    float* out = (float*)d_out;
    float* buf0 = (float*)d_ws;
    float* buf1 = buf0 + NTOT;
    double* slots = (double*)(buf1 + NTOT);

    init_slots<<<1, 64, 0, stream>>>(slots);

    dim3 grid(W_DIM / TW, H_DIM / TH, (D_DIM / TDZ) * NIMG);
    for (int s = 0; s <= NUM_ITER; ++s) {
        const float* ain = (s == 0) ? img : ((s & 1) ? buf0 : buf1);
        float* aout = (s & 1) ? buf1 : buf0;
        skel_step<<<grid, 256, 0, stream>>>(ain, aout, out, slots, s);
    }
}

// Round 13
// 414.984 us; speedup vs baseline: 1.0435x; 1.0435x over previous
//
#include <hip/hip_runtime.h>
#include <math.h>

#define D_DIM 128
#define H_DIM 256
#define W_DIM 256
#define HW (H_DIM * W_DIM)
#define HW4 (HW / 4)
#define NIMG 2
#define NPI (D_DIM * HW)
#define NTOT (NIMG * NPI)

#define TDZ 16
#define TH 16
#define TW 64

#define AW4 18   // aS chunks/row: chunk c -> gx = x0-4+4c  (x0-4 .. x0+67)
#define AH 20    // aS rows: gy = y0-2 .. y0+17
#define EW4 17   // eT chunks/row: chunk c -> gx = x0-2+4c  (x0-2 .. x0+65)
#define EH 18    // eT rows: gy = y0-1 .. y0+16

#define NLOAD (AH * AW4)      // 360 real items
#define NLOADP 384            // padded to 6 full waves
#define NERO  (EH * EW4)      // 306
#define NOUT  (TH * (TW/4))   // 256

#define NUM_ITER 20
#define STOP_THRESH 1e-4

__device__ __forceinline__ float min3f(float a, float b, float c) { return fminf(fminf(a, b), c); }
__device__ __forceinline__ float max3f(float a, float b, float c) { return fmaxf(fmaxf(a, b), c); }
__device__ __forceinline__ float leaky(float x) { return fmaxf(x, 0.01f * x); }

// B1 variants: drain gloads but leave prior-iter stores in flight where safe.
#define BAR_FULL() do { asm volatile("s_waitcnt vmcnt(0) lgkmcnt(0)" ::: "memory"); \
                        __builtin_amdgcn_s_barrier(); \
                        __builtin_amdgcn_sched_barrier(0); } while (0)
#define BAR_VM2()  do { asm volatile("s_waitcnt vmcnt(2) lgkmcnt(0)" ::: "memory"); \
                        __builtin_amdgcn_s_barrier(); \
                        __builtin_amdgcn_sched_barrier(0); } while (0)
#define BAR_VM1()  do { asm volatile("s_waitcnt vmcnt(1) lgkmcnt(0)" ::: "memory"); \
                        __builtin_amdgcn_s_barrier(); \
                        __builtin_amdgcn_sched_barrier(0); } while (0)
// B2: LDS-only drain — keeps global_load_lds for slice i+1 in flight
#define BAR_LDS() do { asm volatile("s_waitcnt lgkmcnt(0)" ::: "memory"); \
                       __builtin_amdgcn_s_barrier(); \
                       __builtin_amdgcn_sched_barrier(0); } while (0)

#define GLOAD_LDS(gp, lp) \
    __builtin_amdgcn_global_load_lds((const __attribute__((address_space(1))) unsigned int*)(gp), \
                                     (__attribute__((address_space(3))) unsigned int*)(lp), 16, 0, 0)

__global__ void init_slots(double* slots) {
    int t = threadIdx.x;
    if (t < 32) slots[t] = 0.0;
    if (t >= 32 && t < 36) ((float*)(slots + 32))[t - 32] = INFINITY;  // 16B +INF cell
}

// R11 structure + issue-order pinning (ggPre oldest -> vmcnt(2) at use leaves
// gloads in flight), aCn hoisted pre-B2, per-block phase stagger, E1 items
// rebalanced across all 4 waves. Tile 64x16x16.
__global__ __launch_bounds__(256) void skel_step(
    const float* __restrict__ a_in,
    float* __restrict__ a_out,
    float* __restrict__ skel,
    double* __restrict__ slots,
    int step)
{
    __shared__ float4 aS4[2][NLOADP];  // 12288 B (ping-pong, lds-load dest)
    __shared__ float4 eT4[NERO];       // 4896 B
    __shared__ float wsum[4];
    __shared__ int s_active;

    const int t = threadIdx.x;

    if (t == 0) {
        int act = 1;
        for (int j = 1; j < step; ++j)
            if (!(slots[j] >= STOP_THRESH * (double)NTOT)) { act = 0; break; }
        s_active = act;
    }
    __syncthreads();
    if (!s_active) return;

    const float* infp = (const float*)(slots + 32);

    // XCD-aware swizzle: grid (4,16,16) = 1024 blocks; XCD k owns swz in
    // [128k,128(k+1)) = full xy coverage of 2 adjacent z-slabs.
    const int lid = blockIdx.x + 4 * (blockIdx.y + 16 * blockIdx.z);
    const int swz = (lid & 7) * 128 + (lid >> 3);
    const int bx = swz & 3;
    const int by = (swz >> 2) & 15;
    const int zz = swz >> 6;           // 0..15
    const int bz = zz & 7, img = zz >> 3;
    const int x0 = bx * TW, y0 = by * TH, z0 = bz * TDZ;

    // phase-stagger co-resident blocks (decorrelate pipe bursts); s_sleep arg
    // is 64-cycle units and must be an immediate.
    switch (lid & 3) {
        case 1: __builtin_amdgcn_s_sleep(4); break;
        case 2: __builtin_amdgcn_s_sleep(8); break;
        case 3: __builtin_amdgcn_s_sleep(12); break;
        default: break;
    }

    const float* in = a_in + (size_t)img * NPI;
    float4* aout4 = (float4*)(a_out + (size_t)img * NPI);
    float4* sk4 = (float4*)(skel + (size_t)img * NPI);

    // ---- load items: q0 = t (all), q1 = 256+t (t<128; q1>=360 -> pad/INF) ----
    int lOff0; bool lVal0;
    {
        int lr = t / AW4, lc = t - lr * AW4;
        int gy = y0 - 2 + lr, gx = x0 - 4 + 4 * lc;
        lVal0 = ((unsigned)gy < H_DIM) && ((unsigned)gx <= (unsigned)(W_DIM - 4));
        lOff0 = gy * W_DIM + gx;
    }
    const bool hasL1 = t < 128;          // wave-uniform
    int lOff1 = 0; bool lVal1 = false;
    if (hasL1) {
        int q = t + 256;
        int lr = q / AW4, lc = q - lr * AW4;
        int gy = y0 - 2 + lr, gx = x0 - 4 + 4 * lc;
        lVal1 = (q < NLOAD) && ((unsigned)gy < H_DIM) && ((unsigned)gx <= (unsigned)(W_DIM - 4));
        lOff1 = gy * W_DIM + gx;
    }
    const int wbase = (t >> 6) << 6;     // wave-uniform LDS base (element units)

    // ---- erode item 0 ----
    int eRd0; bool sA0, sB0, sC0, sD0;
    {
        int mh = t / EW4, ej = t - mh * EW4;
        eRd0 = mh * AW4 + ej;
        int gy = y0 - 1 + mh;
        bool gok = (unsigned)gy < H_DIM;
        int gxb = x0 - 2 + 4 * ej;
        sA0 = gok && ((unsigned)(gxb + 0) < W_DIM);
        sB0 = gok && ((unsigned)(gxb + 1) < W_DIM);
        sC0 = gok && ((unsigned)(gxb + 2) < W_DIM);
        sD0 = gok && ((unsigned)(gxb + 3) < W_DIM);
    }
    // ---- erode item 1: 50 items (256..305) spread over all 4 waves ----
    const int wv = t >> 6, ln = t & 63;
    const int nE1 = (wv < 3) ? 13 : 11;       // 13+13+13+11 = 50
    const bool hasE1 = ln < nE1;
    const int q1 = 256 + 13 * wv + ln;        // valid when hasE1
    int eRd1 = 0, eWr1 = 0; bool sA1 = false, sB1 = false, sC1 = false, sD1 = false;
    if (hasE1) {
        int mh = q1 / EW4, ej = q1 - mh * EW4;
        eRd1 = mh * AW4 + ej;
        eWr1 = q1;
        int gy = y0 - 1 + mh;
        bool gok = (unsigned)gy < H_DIM;
        int gxb = x0 - 2 + 4 * ej;
        sA1 = gok && ((unsigned)(gxb + 0) < W_DIM);
        sB1 = gok && ((unsigned)(gxb + 1) < W_DIM);
        sC1 = gok && ((unsigned)(gxb + 2) < W_DIM);
        sD1 = gok && ((unsigned)(gxb + 3) < W_DIM);
    }

    // ---- out item ----
    const int oh = t >> 4, wq = t & 15;
    const int oRd = oh * EW4 + wq;
    const int oAc = (oh + 2) * AW4 + wq + 1;
    size_t ob = ((size_t)z0 * HW + (size_t)(y0 + oh) * W_DIM + (size_t)x0) / 4 + wq;

    const float INF = INFINITY;
    const float4 inf4 = make_float4(INF, INF, INF, INF);
    const float4 ninf4 = make_float4(-INF, -INF, -INF, -INF);
    float4 m0P2 = inf4, m0P1 = inf4, m1P2 = inf4, m1P1 = inf4;
    float4 xP2 = ninf4, xP1 = ninf4;
    float4 acA = make_float4(0, 0, 0, 0), acB = acA, ecA = acA;
    float lsum = 0.f;

    // ---- prologue: issue slice 0 (z = z0-2) into aS4[0] ----
    {
        int z = z0 - 2;
        bool zok = (unsigned)z < D_DIM;
        const float* p = in + (size_t)z * HW;
        const float* s0 = (zok && lVal0) ? (p + lOff0) : infp;
        GLOAD_LDS(s0, &aS4[0][wbase]);
        if (hasL1) {
            const float* s1 = (zok && lVal1) ? (p + lOff1) : infp;
            GLOAD_LDS(s1, &aS4[0][256 + wbase]);
        }
    }

    for (int i = 0; i < TDZ + 4; ++i) {
        const int cur = i & 1;

        // B1: aS4[cur] loaded. i<5: only gloads outstanding -> full drain.
        // i>=5: leave prior-iter stores (2; 1 at step 20) in flight.
        if (i < 5) { BAR_FULL(); }
        else if (step == NUM_ITER) { BAR_VM1(); }
        else { BAR_VM2(); }

        // early skel prefetch — MUST be oldest VMEM of this iter so its use
        // waits vmcnt(2), leaving the two slice gloads in flight.
        float4 ggPre;
        if (step > 0 && i >= 4) ggPre = sk4[ob];
        __builtin_amdgcn_sched_barrier(0);

        // issue slice i+1 into aS4[cur^1] (stays in flight across B2)
        if (i <= TDZ + 2) {
            int z = z0 - 1 + i;
            bool zok = (unsigned)z < D_DIM;
            const float* p = in + (size_t)z * HW;
            const float* s0 = (zok && lVal0) ? (p + lOff0) : infp;
            GLOAD_LDS(s0, &aS4[cur ^ 1][wbase]);
            if (hasL1) {
                const float* s1 = (zok && lVal1) ? (p + lOff1) : infp;
                GLOAD_LDS(s1, &aS4[cur ^ 1][256 + wbase]);
            }
        }
        __builtin_amdgcn_sched_barrier(0);

        const bool zp = (unsigned)(z0 - 3 + i) < D_DIM;   // erosion slice in volume?

        // ---- erode: a-slices (i-2,i-1,i) -> erosion z0-3+i -> eT4 ----
        {
            const float4* s = aS4[cur];
            float4 a0 = s[eRd0],           b0 = s[eRd0 + 1];
            float4 a1 = s[eRd0 + AW4],     b1 = s[eRd0 + AW4 + 1];
            float4 a2 = s[eRd0 + 2 * AW4], b2 = s[eRd0 + 2 * AW4 + 1];
            float4 va, vb, mC;
            va.x = min3f(a0.x, a1.x, a2.x);
            va.y = min3f(a0.y, a1.y, a2.y);
            va.z = min3f(a0.z, a1.z, a2.z);
            va.w = min3f(a0.w, a1.w, a2.w);
            vb.x = min3f(b0.x, b1.x, b2.x);
            vb.y = min3f(b0.y, b1.y, b2.y);
            vb.z = min3f(b0.z, b1.z, b2.z);
            mC.x = min3f(va.y, va.z, va.w);
            mC.y = min3f(va.z, va.w, vb.x);
            mC.z = min3f(va.w, vb.x, vb.y);
            mC.w = min3f(vb.x, vb.y, vb.z);
            if (i >= 2 && zp) {
                float4 e;
                e.x = sA0 ? min3f(m0P2.x, m0P1.x, mC.x) : -INF;
                e.y = sB0 ? min3f(m0P2.y, m0P1.y, mC.y) : -INF;
                e.z = sC0 ? min3f(m0P2.z, m0P1.z, mC.z) : -INF;
                e.w = sD0 ? min3f(m0P2.w, m0P1.w, mC.w) : -INF;
                eT4[t] = e;
            }
            m0P2 = m0P1; m0P1 = mC;
        }
        if (hasE1) {
            const float4* s = aS4[cur];
            float4 a0 = s[eRd1],           b0 = s[eRd1 + 1];
            float4 a1 = s[eRd1 + AW4],     b1 = s[eRd1 + AW4 + 1];
            float4 a2 = s[eRd1 + 2 * AW4], b2 = s[eRd1 + 2 * AW4 + 1];
            float4 va, vb, mC;
            va.x = min3f(a0.x, a1.x, a2.x);
            va.y = min3f(a0.y, a1.y, a2.y);
            va.z = min3f(a0.z, a1.z, a2.z);
            va.w = min3f(a0.w, a1.w, a2.w);
            vb.x = min3f(b0.x, b1.x, b2.x);
            vb.y = min3f(b0.y, b1.y, b2.y);
            vb.z = min3f(b0.z, b1.z, b2.z);
            mC.x = min3f(va.y, va.z, va.w);
            mC.y = min3f(va.z, va.w, vb.x);
            mC.z = min3f(va.w, vb.x, vb.y);
            mC.w = min3f(vb.x, vb.y, vb.z);
            if (i >= 2 && zp) {
                float4 e;
                e.x = sA1 ? min3f(m1P2.x, m1P1.x, mC.x) : -INF;
                e.y = sB1 ? min3f(m1P2.y, m1P1.y, mC.y) : -INF;
                e.z = sC1 ? min3f(m1P2.z, m1P1.z, mC.z) : -INF;
                e.w = sD1 ? min3f(m1P2.w, m1P1.w, mC.w) : -INF;
                eT4[eWr1] = e;
            }
            m1P2 = m1P1; m1P1 = mC;
        }

        // aCn read issued pre-B2 (aS4[cur] is stable through this iteration);
        // result consumed after the barrier.
        const float4 aCn = aS4[cur][oAc];

        BAR_LDS();  // B2: eT4 ready (vmcnt NOT drained — slice i+1 still in flight)

        // ---- out: dilate erosion slice z0-3+i; output z0-4+i ----
        {
            float4 xC, ecB;
            if (i >= 2 && zp) {
                float4 A0 = eT4[oRd],           B0 = eT4[oRd + 1];
                float4 A1 = eT4[oRd + EW4],     B1 = eT4[oRd + EW4 + 1];
                float4 A2 = eT4[oRd + 2 * EW4], B2 = eT4[oRd + 2 * EW4 + 1];
                float4 va, vb;
                va.x = max3f(A0.x, A1.x, A2.x);
                va.y = max3f(A0.y, A1.y, A2.y);
                va.z = max3f(A0.z, A1.z, A2.z);
                va.w = max3f(A0.w, A1.w, A2.w);
                vb.x = max3f(B0.x, B1.x, B2.x);
                vb.y = max3f(B0.y, B1.y, B2.y);
                vb.z = max3f(B0.z, B1.z, B2.z);
                xC.x = max3f(va.y, va.z, va.w);
                xC.y = max3f(va.z, va.w, vb.x);
                xC.z = max3f(va.w, vb.x, vb.y);
                xC.w = max3f(vb.x, vb.y, vb.z);
                ecB.x = A1.z; ecB.y = A1.w; ecB.z = B1.x; ecB.w = B1.y;
            } else {
                xC = ninf4; ecB = ninf4;
            }

            if (i >= 4) {
                float4 dl;
                dl.x = leaky(acA.x - max3f(xP2.x, xP1.x, xC.x));
                dl.y = leaky(acA.y - max3f(xP2.y, xP1.y, xC.y));
                dl.z = leaky(acA.z - max3f(xP2.z, xP1.z, xC.z));
                dl.w = leaky(acA.w - max3f(xP2.w, xP1.w, xC.w));
                if (step < NUM_ITER) aout4[ob] = ecA;
                if (step == 0) {
                    sk4[ob] = dl;
                } else {
                    float4 gg = ggPre;
                    float4 up, gn;
                    up.x = leaky(dl.x - gg.x * dl.x); gn.x = gg.x + up.x;
                    up.y = leaky(dl.y - gg.y * dl.y); gn.y = gg.y + up.y;
                    up.z = leaky(dl.z - gg.z * dl.z); gn.z = gg.z + up.z;
                    up.w = leaky(dl.w - gg.w * dl.w); gn.w = gg.w + up.w;
                    sk4[ob] = gn;
                    if (step == 1)
                        lsum += fabsf(gn.x) + fabsf(gn.y) + fabsf(gn.z) + fabsf(gn.w);
                    else
                        lsum += fabsf(up.x) + fabsf(up.y) + fabsf(up.z) + fabsf(up.w);
                }
                ob += HW4;
            }
            xP2 = xP1; xP1 = xC;
            acA = acB; acB = aCn;
            ecA = ecB;
        }
    }

    // dn reduction: one double atomic per block
    if (step > 0) {
        #pragma unroll
        for (int off = 32; off > 0; off >>= 1)
            lsum += __shfl_down(lsum, off, 64);
        const int lane = t & 63, wid = t >> 6;
        if (lane == 0) wsum[wid] = lsum;
        __syncthreads();
        if (t == 0) {
            float b = wsum[0] + wsum[1] + wsum[2] + wsum[3];
            atomicAdd(&slots[step], (double)b);
        }
    }
}

extern "C" void kernel_launch(void* const* d_in, const int* in_sizes, int n_in,
                              void* d_out, int out_size, void* d_ws, size_t ws_size,
                              hipStream_t stream) {
    const float* img = (const float*)d_in[0];
    float* out = (float*)d_out;
    float* buf0 = (float*)d_ws;
    float* buf1 = buf0 + NTOT;
    double* slots = (double*)(buf1 + NTOT);

    init_slots<<<1, 64, 0, stream>>>(slots);

    dim3 grid(W_DIM / TW, H_DIM / TH, (D_DIM / TDZ) * NIMG);
    for (int s = 0; s <= NUM_ITER; ++s) {
        const float* ain = (s == 0) ? img : ((s & 1) ? buf0 : buf1);
        float* aout = (s & 1) ? buf1 : buf0;
        skel_step<<<grid, 256, 0, stream>>>(ain, aout, out, slots, s);
    }
}

// Round 14
// 387.138 us; speedup vs baseline: 1.1185x; 1.0719x over previous
//
#include <hip/hip_runtime.h>
#include <math.h>

#define D_DIM 128
#define H_DIM 256
#define W_DIM 256
#define HW (H_DIM * W_DIM)
#define HW4 (HW / 4)
#define NIMG 2
#define NPI (D_DIM * HW)
#define NTOT (NIMG * NPI)

#define TDZ 16
#define TH 16
#define TW 64

#define AW4R 18  // real aS chunks/row: chunk c -> gx = x0-4+4c (x0-4 .. x0+67)
#define AW4 19   // padded aS row stride (19 mod 8 = 3 -> no cross-row bank alias)
#define AH 20    // aS rows: gy = y0-2 .. y0+17
#define EW4R 17  // real eT chunks/row: chunk c -> gx = x0-2+4c (x0-2 .. x0+65)
#define EW4 19   // padded eT row stride
#define EH 18    // eT rows: gy = y0-1 .. y0+16

#define NLOADLIN (AH * AW4)   // 380 padded-linear load slots
#define NLOADP 384            // rounded to 6 full waves
#define NERO  (EH * EW4R)     // 306 real erode items
#define NOUT  (TH * (TW/4))   // 256

#define NUM_ITER 20
#define STOP_THRESH 1e-4

__device__ __forceinline__ float min3f(float a, float b, float c) { return fminf(fminf(a, b), c); }
__device__ __forceinline__ float max3f(float a, float b, float c) { return fmaxf(fmaxf(a, b), c); }
__device__ __forceinline__ float leaky(float x) { return fmaxf(x, 0.01f * x); }

// B1 variants: drain gloads but leave prior-iter stores in flight where safe.
#define BAR_FULL() do { asm volatile("s_waitcnt vmcnt(0) lgkmcnt(0)" ::: "memory"); \
                        __builtin_amdgcn_s_barrier(); \
                        __builtin_amdgcn_sched_barrier(0); } while (0)
#define BAR_VM2()  do { asm volatile("s_waitcnt vmcnt(2) lgkmcnt(0)" ::: "memory"); \
                        __builtin_amdgcn_s_barrier(); \
                        __builtin_amdgcn_sched_barrier(0); } while (0)
#define BAR_VM1()  do { asm volatile("s_waitcnt vmcnt(1) lgkmcnt(0)" ::: "memory"); \
                        __builtin_amdgcn_s_barrier(); \
                        __builtin_amdgcn_sched_barrier(0); } while (0)
// B2: LDS-only drain — keeps global_load_lds for slice i+1 in flight
#define BAR_LDS() do { asm volatile("s_waitcnt lgkmcnt(0)" ::: "memory"); \
                       __builtin_amdgcn_s_barrier(); \
                       __builtin_amdgcn_sched_barrier(0); } while (0)

#define GLOAD_LDS(gp, lp) \
    __builtin_amdgcn_global_load_lds((const __attribute__((address_space(1))) unsigned int*)(gp), \
                                     (__attribute__((address_space(3))) unsigned int*)(lp), 16, 0, 0)

__global__ void init_slots(double* slots) {
    int t = threadIdx.x;
    if (t < 32) slots[t] = 0.0;
    if (t >= 32 && t < 36) ((float*)(slots + 32))[t - 32] = INFINITY;  // 16B +INF cell
}

// R11 structure with bank-conflict-free padded LDS strides (19 chunks). The
// global_load_lds dest stays LINEAR in the padded index space; the global
// SOURCE is remapped per-lane to the padded order (pad slots -> +INF cell).
// Tile 64x16x16, all 256 threads active in every stage.
__global__ __launch_bounds__(256) void skel_step(
    const float* __restrict__ a_in,
    float* __restrict__ a_out,
    float* __restrict__ skel,
    double* __restrict__ slots,
    int step)
{
    __shared__ float4 aS4[2][NLOADP];  // 12288 B (ping-pong, lds-load dest)
    __shared__ float4 eT4[EH * EW4];   // 342 f4 = 5472 B (padded rows)
    __shared__ float wsum[4];
    __shared__ int s_active;

    const int t = threadIdx.x;

    if (t == 0) {
        int act = 1;
        for (int j = 1; j < step; ++j)
            if (!(slots[j] >= STOP_THRESH * (double)NTOT)) { act = 0; break; }
        s_active = act;
    }
    __syncthreads();
    if (!s_active) return;

    const float* infp = (const float*)(slots + 32);

    // XCD-aware swizzle: grid (4,16,16) = 1024 blocks; XCD k owns swz in
    // [128k,128(k+1)) = full xy coverage of 2 adjacent z-slabs.
    const int lid = blockIdx.x + 4 * (blockIdx.y + 16 * blockIdx.z);
    const int swz = (lid & 7) * 128 + (lid >> 3);
    const int bx = swz & 3;
    const int by = (swz >> 2) & 15;
    const int zz = swz >> 6;           // 0..15
    const int bz = zz & 7, img = zz >> 3;
    const int x0 = bx * TW, y0 = by * TH, z0 = bz * TDZ;

    const float* in = a_in + (size_t)img * NPI;
    float4* aout4 = (float4*)(a_out + (size_t)img * NPI);
    float4* sk4 = (float4*)(skel + (size_t)img * NPI);

    // ---- load items in PADDED-linear order: q0 = t, q1 = t+256 (t<128) ----
    int lOff0; bool lVal0;
    {
        int lr = t / AW4, lc = t - lr * AW4;
        int gy = y0 - 2 + lr, gx = x0 - 4 + 4 * lc;
        lVal0 = (lc < AW4R) && ((unsigned)gy < H_DIM) && ((unsigned)gx <= (unsigned)(W_DIM - 4));
        lOff0 = gy * W_DIM + gx;
    }
    const bool hasL1 = t < 128;          // wave-uniform
    int lOff1 = 0; bool lVal1 = false;
    if (hasL1) {
        int q = t + 256;
        int lr = q / AW4, lc = q - lr * AW4;
        int gy = y0 - 2 + lr, gx = x0 - 4 + 4 * lc;
        lVal1 = (q < NLOADLIN) && (lc < AW4R) && ((unsigned)gy < H_DIM)
                && ((unsigned)gx <= (unsigned)(W_DIM - 4));
        lOff1 = gy * W_DIM + gx;
    }
    const int wbase = (t >> 6) << 6;     // wave-uniform LDS base (element units)

    // ---- erode items (real 17-wide grid; padded stride-19 addressing) ----
    int eRd0, eWr0; bool sA0, sB0, sC0, sD0;
    {
        int mh = t / EW4R, ej = t - mh * EW4R;
        eRd0 = mh * AW4 + ej;
        eWr0 = mh * EW4 + ej;
        int gy = y0 - 1 + mh;
        bool gok = (unsigned)gy < H_DIM;
        int gxb = x0 - 2 + 4 * ej;
        sA0 = gok && ((unsigned)(gxb + 0) < W_DIM);
        sB0 = gok && ((unsigned)(gxb + 1) < W_DIM);
        sC0 = gok && ((unsigned)(gxb + 2) < W_DIM);
        sD0 = gok && ((unsigned)(gxb + 3) < W_DIM);
    }
    const bool hasE1 = t < (NERO - 256);    // t < 50
    int eRd1 = 0, eWr1 = 0; bool sA1 = false, sB1 = false, sC1 = false, sD1 = false;
    if (hasE1) {
        int q = t + 256;
        int mh = q / EW4R, ej = q - mh * EW4R;
        eRd1 = mh * AW4 + ej;
        eWr1 = mh * EW4 + ej;
        int gy = y0 - 1 + mh;
        bool gok = (unsigned)gy < H_DIM;
        int gxb = x0 - 2 + 4 * ej;
        sA1 = gok && ((unsigned)(gxb + 0) < W_DIM);
        sB1 = gok && ((unsigned)(gxb + 1) < W_DIM);
        sC1 = gok && ((unsigned)(gxb + 2) < W_DIM);
        sD1 = gok && ((unsigned)(gxb + 3) < W_DIM);
    }

    // ---- out item ----
    const int oh = t >> 4, wq = t & 15;
    const int oRd = oh * EW4 + wq;
    const int oAc = (oh + 2) * AW4 + wq + 1;
    size_t ob = ((size_t)z0 * HW + (size_t)(y0 + oh) * W_DIM + (size_t)x0) / 4 + wq;

    const float INF = INFINITY;
    const float4 inf4 = make_float4(INF, INF, INF, INF);
    const float4 ninf4 = make_float4(-INF, -INF, -INF, -INF);
    float4 m0P2 = inf4, m0P1 = inf4, m1P2 = inf4, m1P1 = inf4;
    float4 xP2 = ninf4, xP1 = ninf4;
    float4 acA = make_float4(0, 0, 0, 0), acB = acA, ecA = acA;
    float lsum = 0.f;

    // ---- prologue: issue slice 0 (z = z0-2) into aS4[0] ----
    {
        int z = z0 - 2;
        bool zok = (unsigned)z < D_DIM;
        const float* p = in + (size_t)z * HW;
        const float* s0 = (zok && lVal0) ? (p + lOff0) : infp;
        GLOAD_LDS(s0, &aS4[0][wbase]);
        if (hasL1) {
            const float* s1 = (zok && lVal1) ? (p + lOff1) : infp;
            GLOAD_LDS(s1, &aS4[0][256 + wbase]);
        }
    }

    for (int i = 0; i < TDZ + 4; ++i) {
        const int cur = i & 1;

        // B1: aS4[cur] loaded. i<5: only gloads outstanding -> full drain.
        // i>=5: leave prior-iter stores (2; 1 at step 20) in flight.
        if (i < 5) { BAR_FULL(); }
        else if (step == NUM_ITER) { BAR_VM1(); }
        else { BAR_VM2(); }

        // early skel prefetch — oldest VMEM of this iter (pinned) so its use
        // waits vmcnt(2), leaving the two slice gloads in flight.
        float4 ggPre;
        if (step > 0 && i >= 4) ggPre = sk4[ob];
        __builtin_amdgcn_sched_barrier(0);

        // issue slice i+1 into aS4[cur^1] (stays in flight across B2)
        if (i <= TDZ + 2) {
            int z = z0 - 1 + i;
            bool zok = (unsigned)z < D_DIM;
            const float* p = in + (size_t)z * HW;
            const float* s0 = (zok && lVal0) ? (p + lOff0) : infp;
            GLOAD_LDS(s0, &aS4[cur ^ 1][wbase]);
            if (hasL1) {
                const float* s1 = (zok && lVal1) ? (p + lOff1) : infp;
                GLOAD_LDS(s1, &aS4[cur ^ 1][256 + wbase]);
            }
        }
        __builtin_amdgcn_sched_barrier(0);

        const bool zp = (unsigned)(z0 - 3 + i) < D_DIM;   // erosion slice in volume?

        // ---- erode: a-slices (i-2,i-1,i) -> erosion z0-3+i -> eT4 ----
        {
            const float4* s = aS4[cur];
            float4 a0 = s[eRd0],           b0 = s[eRd0 + 1];
            float4 a1 = s[eRd0 + AW4],     b1 = s[eRd0 + AW4 + 1];
            float4 a2 = s[eRd0 + 2 * AW4], b2 = s[eRd0 + 2 * AW4 + 1];
            float4 va, vb, mC;
            va.x = min3f(a0.x, a1.x, a2.x);
            va.y = min3f(a0.y, a1.y, a2.y);
            va.z = min3f(a0.z, a1.z, a2.z);
            va.w = min3f(a0.w, a1.w, a2.w);
            vb.x = min3f(b0.x, b1.x, b2.x);
            vb.y = min3f(b0.y, b1.y, b2.y);
            vb.z = min3f(b0.z, b1.z, b2.z);
            mC.x = min3f(va.y, va.z, va.w);
            mC.y = min3f(va.z, va.w, vb.x);
            mC.z = min3f(va.w, vb.x, vb.y);
            mC.w = min3f(vb.x, vb.y, vb.z);
            if (i >= 2 && zp) {
                float4 e;
                e.x = sA0 ? min3f(m0P2.x, m0P1.x, mC.x) : -INF;
                e.y = sB0 ? min3f(m0P2.y, m0P1.y, mC.y) : -INF;
                e.z = sC0 ? min3f(m0P2.z, m0P1.z, mC.z) : -INF;
                e.w = sD0 ? min3f(m0P2.w, m0P1.w, mC.w) : -INF;
                eT4[eWr0] = e;
            }
            m0P2 = m0P1; m0P1 = mC;
        }
        if (hasE1) {
            const float4* s = aS4[cur];
            float4 a0 = s[eRd1],           b0 = s[eRd1 + 1];
            float4 a1 = s[eRd1 + AW4],     b1 = s[eRd1 + AW4 + 1];
            float4 a2 = s[eRd1 + 2 * AW4], b2 = s[eRd1 + 2 * AW4 + 1];
            float4 va, vb, mC;
            va.x = min3f(a0.x, a1.x, a2.x);
            va.y = min3f(a0.y, a1.y, a2.y);
            va.z = min3f(a0.z, a1.z, a2.z);
            va.w = min3f(a0.w, a1.w, a2.w);
            vb.x = min3f(b0.x, b1.x, b2.x);
            vb.y = min3f(b0.y, b1.y, b2.y);
            vb.z = min3f(b0.z, b1.z, b2.z);
            mC.x = min3f(va.y, va.z, va.w);
            mC.y = min3f(va.z, va.w, vb.x);
            mC.z = min3f(va.w, vb.x, vb.y);
            mC.w = min3f(vb.x, vb.y, vb.z);
            if (i >= 2 && zp) {
                float4 e;
                e.x = sA1 ? min3f(m1P2.x, m1P1.x, mC.x) : -INF;
                e.y = sB1 ? min3f(m1P2.y, m1P1.y, mC.y) : -INF;
                e.z = sC1 ? min3f(m1P2.z, m1P1.z, mC.z) : -INF;
                e.w = sD1 ? min3f(m1P2.w, m1P1.w, mC.w) : -INF;
                eT4[eWr1] = e;
            }
            m1P2 = m1P1; m1P1 = mC;
        }

        BAR_LDS();  // B2: eT4 ready (vmcnt NOT drained — slice i+1 still in flight)

        // ---- out: dilate erosion slice z0-3+i; output z0-4+i ----
        {
            const float4 aCn = aS4[cur][oAc];
            float4 xC, ecB;
            if (i >= 2 && zp) {
                float4 A0 = eT4[oRd],           B0 = eT4[oRd + 1];
                float4 A1 = eT4[oRd + EW4],     B1 = eT4[oRd + EW4 + 1];
                float4 A2 = eT4[oRd + 2 * EW4], B2 = eT4[oRd + 2 * EW4 + 1];
                float4 va, vb;
                va.x = max3f(A0.x, A1.x, A2.x);
                va.y = max3f(A0.y, A1.y, A2.y);
                va.z = max3f(A0.z, A1.z, A2.z);
                va.w = max3f(A0.w, A1.w, A2.w);
                vb.x = max3f(B0.x, B1.x, B2.x);
                vb.y = max3f(B0.y, B1.y, B2.y);
                vb.z = max3f(B0.z, B1.z, B2.z);
                xC.x = max3f(va.y, va.z, va.w);
                xC.y = max3f(va.z, va.w, vb.x);
                xC.z = max3f(va.w, vb.x, vb.y);
                xC.w = max3f(vb.x, vb.y, vb.z);
                ecB.x = A1.z; ecB.y = A1.w; ecB.z = B1.x; ecB.w = B1.y;
            } else {
                xC = ninf4; ecB = ninf4;
            }

            if (i >= 4) {
                float4 dl;
                dl.x = leaky(acA.x - max3f(xP2.x, xP1.x, xC.x));
                dl.y = leaky(acA.y - max3f(xP2.y, xP1.y, xC.y));
                dl.z = leaky(acA.z - max3f(xP2.z, xP1.z, xC.z));
                dl.w = leaky(acA.w - max3f(xP2.w, xP1.w, xC.w));
                if (step < NUM_ITER) aout4[ob] = ecA;
                if (step == 0) {
                    sk4[ob] = dl;
                } else {
                    float4 gg = ggPre;
                    float4 up, gn;
                    up.x = leaky(dl.x - gg.x * dl.x); gn.x = gg.x + up.x;
                    up.y = leaky(dl.y - gg.y * dl.y); gn.y = gg.y + up.y;
                    up.z = leaky(dl.z - gg.z * dl.z); gn.z = gg.z + up.z;
                    up.w = leaky(dl.w - gg.w * dl.w); gn.w = gg.w + up.w;
                    sk4[ob] = gn;
                    if (step == 1)
                        lsum += fabsf(gn.x) + fabsf(gn.y) + fabsf(gn.z) + fabsf(gn.w);
                    else
                        lsum += fabsf(up.x) + fabsf(up.y) + fabsf(up.z) + fabsf(up.w);
                }
                ob += HW4;
            }
            xP2 = xP1; xP1 = xC;
            acA = acB; acB = aCn;
            ecA = ecB;
        }
    }

    // dn reduction: one double atomic per block
    if (step > 0) {
        #pragma unroll
        for (int off = 32; off > 0; off >>= 1)
            lsum += __shfl_down(lsum, off, 64);
        const int lane = t & 63, wid = t >> 6;
        if (lane == 0) wsum[wid] = lsum;
        __syncthreads();
        if (t == 0) {
            float b = wsum[0] + wsum[1] + wsum[2] + wsum[3];
            atomicAdd(&slots[step], (double)b);
        }
    }
}

extern "C" void kernel_launch(void* const* d_in, const int* in_sizes, int n_in,
                              void* d_out, int out_size, void* d_ws, size_t ws_size,
                              hipStream_t stream) {
    const float* img = (const float*)d_in[0];
    float* out = (float*)d_out;
    float* buf0 = (float*)d_ws;
    float* buf1 = buf0 + NTOT;
    double* slots = (double*)(buf1 + NTOT);

    init_slots<<<1, 64, 0, stream>>>(slots);

    dim3 grid(W_DIM / TW, H_DIM / TH, (D_DIM / TDZ) * NIMG);
    for (int s = 0; s <= NUM_ITER; ++s) {
        const float* ain = (s == 0) ? img : ((s & 1) ? buf0 : buf1);
        float* aout = (s & 1) ? buf1 : buf0;
        skel_step<<<grid, 256, 0, stream>>>(ain, aout, out, slots, s);
    }
}

// Round 15
// 383.408 us; speedup vs baseline: 1.1294x; 1.0097x over previous
//
#include <hip/hip_runtime.h>
#include <math.h>

#define D_DIM 128
#define H_DIM 256
#define W_DIM 256
#define HW (H_DIM * W_DIM)
#define HW4 (HW / 4)
#define NIMG 2
#define NPI (D_DIM * HW)
#define NTOT (NIMG * NPI)

#define TDZ 16
#define TH 16
#define TW 64

#define AW4R 18  // real aS chunks/row: chunk c -> gx = x0-4+4c (x0-4 .. x0+67)
#define AW4 19   // padded aS row stride
#define AH 20    // aS rows: gy = y0-2 .. y0+17
#define EW4R 17  // real eT chunks/row: chunk c -> gx = x0-2+4c (x0-2 .. x0+65)
#define EW4 19   // padded eT row stride
#define EH 18    // eT rows: gy = y0-1 .. y0+16

#define NLOADLIN (AH * AW4)   // 380 padded-linear load slots
#define NLOADP 384            // rounded to 6 full waves
#define NERO  (EH * EW4R)     // 306 real erode items
#define NOUT  (TH * (TW/4))   // 256

#define NUM_ITER 20
#define STOP_THRESH 1e-4

__device__ __forceinline__ float min3f(float a, float b, float c) { return fminf(fminf(a, b), c); }
__device__ __forceinline__ float max3f(float a, float b, float c) { return fmaxf(fmaxf(a, b), c); }
__device__ __forceinline__ float leaky(float x) { return fmaxf(x, 0.01f * x); }

// B1 variants: drain gloads but leave prior-pair stores in flight where safe.
#define BAR_FULL() do { asm volatile("s_waitcnt vmcnt(0) lgkmcnt(0)" ::: "memory"); \
                        __builtin_amdgcn_s_barrier(); \
                        __builtin_amdgcn_sched_barrier(0); } while (0)
#define BAR_VM4()  do { asm volatile("s_waitcnt vmcnt(4) lgkmcnt(0)" ::: "memory"); \
                        __builtin_amdgcn_s_barrier(); \
                        __builtin_amdgcn_sched_barrier(0); } while (0)
#define BAR_VM2()  do { asm volatile("s_waitcnt vmcnt(2) lgkmcnt(0)" ::: "memory"); \
                        __builtin_amdgcn_s_barrier(); \
                        __builtin_amdgcn_sched_barrier(0); } while (0)
// B2: LDS-only drain — keeps global_load_lds for the next pair in flight
#define BAR_LDS() do { asm volatile("s_waitcnt lgkmcnt(0)" ::: "memory"); \
                       __builtin_amdgcn_s_barrier(); \
                       __builtin_amdgcn_sched_barrier(0); } while (0)

#define GLOAD_LDS(gp, lp) \
    __builtin_amdgcn_global_load_lds((const __attribute__((address_space(1))) unsigned int*)(gp), \
                                     (__attribute__((address_space(3))) unsigned int*)(lp), 16, 0, 0)

__global__ void init_slots(double* slots) {
    int t = threadIdx.x;
    if (t < 32) slots[t] = 0.0;
    if (t >= 32 && t < 36) ((float*)(slots + 32))[t - 32] = INFINITY;  // 16B +INF cell
}

// R14 dataflow z-unrolled x2: per pair k, slices i0=2k / i1=2k+1 share one
// B1/B2 barrier pair (halves per-slice sync+drain floor). aS4 has 4 slice
// slots (pair ping-pong); eT4 has 2 fixed slots. Next pair's gloads stay in
// flight across B2; counted vmcnt(4) leaves the 4 output stores in flight.
__global__ __launch_bounds__(256) void skel_step(
    const float* __restrict__ a_in,
    float* __restrict__ a_out,
    float* __restrict__ skel,
    double* __restrict__ slots,
    int step)
{
    __shared__ float4 aS4[4][NLOADP];  // 24576 B (4 slice slots, gload dest)
    __shared__ float4 eT4[2][EH * EW4];// 10944 B (padded rows)
    __shared__ float wsum[4];
    __shared__ int s_active;

    const int t = threadIdx.x;

    if (t == 0) {
        int act = 1;
        for (int j = 1; j < step; ++j)
            if (!(slots[j] >= STOP_THRESH * (double)NTOT)) { act = 0; break; }
        s_active = act;
    }
    __syncthreads();
    if (!s_active) return;

    const float* infp = (const float*)(slots + 32);

    // XCD-aware swizzle: grid (4,16,16) = 1024 blocks; XCD k owns swz in
    // [128k,128(k+1)) = full xy coverage of 2 adjacent z-slabs.
    const int lid = blockIdx.x + 4 * (blockIdx.y + 16 * blockIdx.z);
    const int swz = (lid & 7) * 128 + (lid >> 3);
    const int bx = swz & 3;
    const int by = (swz >> 2) & 15;
    const int zz = swz >> 6;           // 0..15
    const int bz = zz & 7, img = zz >> 3;
    const int x0 = bx * TW, y0 = by * TH, z0 = bz * TDZ;

    const float* in = a_in + (size_t)img * NPI;
    float4* aout4 = (float4*)(a_out + (size_t)img * NPI);
    float4* sk4 = (float4*)(skel + (size_t)img * NPI);

    // ---- load items in PADDED-linear order: q0 = t, q1 = t+256 (t<128) ----
    int lOff0; bool lVal0;
    {
        int lr = t / AW4, lc = t - lr * AW4;
        int gy = y0 - 2 + lr, gx = x0 - 4 + 4 * lc;
        lVal0 = (lc < AW4R) && ((unsigned)gy < H_DIM) && ((unsigned)gx <= (unsigned)(W_DIM - 4));
        lOff0 = gy * W_DIM + gx;
    }
    const bool hasL1 = t < 128;          // wave-uniform
    int lOff1 = 0; bool lVal1 = false;
    if (hasL1) {
        int q = t + 256;
        int lr = q / AW4, lc = q - lr * AW4;
        int gy = y0 - 2 + lr, gx = x0 - 4 + 4 * lc;
        lVal1 = (q < NLOADLIN) && (lc < AW4R) && ((unsigned)gy < H_DIM)
                && ((unsigned)gx <= (unsigned)(W_DIM - 4));
        lOff1 = gy * W_DIM + gx;
    }
    const int wbase = (t >> 6) << 6;     // wave-uniform LDS base (element units)

    // ---- erode items (real 17-wide grid; padded stride-19 addressing) ----
    int eRd0, eWr0; bool sA0, sB0, sC0, sD0;
    {
        int mh = t / EW4R, ej = t - mh * EW4R;
        eRd0 = mh * AW4 + ej;
        eWr0 = mh * EW4 + ej;
        int gy = y0 - 1 + mh;
        bool gok = (unsigned)gy < H_DIM;
        int gxb = x0 - 2 + 4 * ej;
        sA0 = gok && ((unsigned)(gxb + 0) < W_DIM);
        sB0 = gok && ((unsigned)(gxb + 1) < W_DIM);
        sC0 = gok && ((unsigned)(gxb + 2) < W_DIM);
        sD0 = gok && ((unsigned)(gxb + 3) < W_DIM);
    }
    const bool hasE1 = t < (NERO - 256);    // t < 50
    int eRd1 = 0, eWr1 = 0; bool sA1 = false, sB1 = false, sC1 = false, sD1 = false;
    if (hasE1) {
        int q = t + 256;
        int mh = q / EW4R, ej = q - mh * EW4R;
        eRd1 = mh * AW4 + ej;
        eWr1 = mh * EW4 + ej;
        int gy = y0 - 1 + mh;
        bool gok = (unsigned)gy < H_DIM;
        int gxb = x0 - 2 + 4 * ej;
        sA1 = gok && ((unsigned)(gxb + 0) < W_DIM);
        sB1 = gok && ((unsigned)(gxb + 1) < W_DIM);
        sC1 = gok && ((unsigned)(gxb + 2) < W_DIM);
        sD1 = gok && ((unsigned)(gxb + 3) < W_DIM);
    }

    // ---- out item ----
    const int oh = t >> 4, wq = t & 15;
    const int oRd = oh * EW4 + wq;
    const int oAc = (oh + 2) * AW4 + wq + 1;
    size_t ob = ((size_t)z0 * HW + (size_t)(y0 + oh) * W_DIM + (size_t)x0) / 4 + wq;

    const float INF = INFINITY;
    const float4 ninf4 = make_float4(-INF, -INF, -INF, -INF);
    const float4 inf4 = make_float4(INF, INF, INF, INF);
    // rolling chains (advance by 2 per pair)
    float4 m0P2 = inf4, m0P1 = inf4, m1P2 = inf4, m1P1 = inf4;
    float4 xP2 = ninf4, xP1 = ninf4;
    float4 acP2 = make_float4(0, 0, 0, 0), acP1 = acP2, ecP = acP2;
    float lsum = 0.f;

    // ---- prologue: issue slices 0,1 into slots 0,1 ----
    for (int s = 0; s < 2; ++s) {
        int z = z0 - 2 + s;
        bool zok = (unsigned)z < D_DIM;
        const float* p = in + (size_t)z * HW;
        const float* s0 = (zok && lVal0) ? (p + lOff0) : infp;
        GLOAD_LDS(s0, &aS4[s][wbase]);
        if (hasL1) {
            const float* s1 = (zok && lVal1) ? (p + lOff1) : infp;
            GLOAD_LDS(s1, &aS4[s][256 + wbase]);
        }
    }

    #define ERODE_SLICE(SLOT, ZPV, DO_E, ETI, mP2v, mP1v, m1P2v, m1P1v)            \
    do {                                                                           \
        const float4* s_ = aS4[SLOT];                                              \
        float4 a0 = s_[eRd0],           b0 = s_[eRd0 + 1];                         \
        float4 a1 = s_[eRd0 + AW4],     b1 = s_[eRd0 + AW4 + 1];                   \
        float4 a2 = s_[eRd0 + 2 * AW4], b2 = s_[eRd0 + 2 * AW4 + 1];               \
        float4 va, vb, mC;                                                         \
        va.x = min3f(a0.x, a1.x, a2.x); va.y = min3f(a0.y, a1.y, a2.y);            \
        va.z = min3f(a0.z, a1.z, a2.z); va.w = min3f(a0.w, a1.w, a2.w);            \
        vb.x = min3f(b0.x, b1.x, b2.x); vb.y = min3f(b0.y, b1.y, b2.y);            \
        vb.z = min3f(b0.z, b1.z, b2.z);                                            \
        mC.x = min3f(va.y, va.z, va.w); mC.y = min3f(va.z, va.w, vb.x);            \
        mC.z = min3f(va.w, vb.x, vb.y); mC.w = min3f(vb.x, vb.y, vb.z);            \
        if ((DO_E) && (ZPV)) {                                                     \
            float4 e;                                                              \
            e.x = sA0 ? min3f(mP2v.x, mP1v.x, mC.x) : -INF;                        \
            e.y = sB0 ? min3f(mP2v.y, mP1v.y, mC.y) : -INF;                        \
            e.z = sC0 ? min3f(mP2v.z, mP1v.z, mC.z) : -INF;                        \
            e.w = sD0 ? min3f(mP2v.w, mP1v.w, mC.w) : -INF;                        \
            eT4[ETI][eWr0] = e;                                                    \
        }                                                                          \
        mP2v = mP1v; mP1v = mC;                                                    \
        if (hasE1) {                                                               \
            float4 c0 = s_[eRd1],           d0 = s_[eRd1 + 1];                     \
            float4 c1 = s_[eRd1 + AW4],     d1 = s_[eRd1 + AW4 + 1];               \
            float4 c2 = s_[eRd1 + 2 * AW4], d2 = s_[eRd1 + 2 * AW4 + 1];           \
            float4 wa, wb, nC;                                                     \
            wa.x = min3f(c0.x, c1.x, c2.x); wa.y = min3f(c0.y, c1.y, c2.y);        \
            wa.z = min3f(c0.z, c1.z, c2.z); wa.w = min3f(c0.w, c1.w, c2.w);        \
            wb.x = min3f(d0.x, d1.x, d2.x); wb.y = min3f(d0.y, d1.y, d2.y);        \
            wb.z = min3f(d0.z, d1.z, d2.z);                                        \
            nC.x = min3f(wa.y, wa.z, wa.w); nC.y = min3f(wa.z, wa.w, wb.x);        \
            nC.z = min3f(wa.w, wb.x, wb.y); nC.w = min3f(wb.x, wb.y, wb.z);        \
            if ((DO_E) && (ZPV)) {                                                 \
                float4 e;                                                          \
                e.x = sA1 ? min3f(m1P2v.x, m1P1v.x, nC.x) : -INF;                  \
                e.y = sB1 ? min3f(m1P2v.y, m1P1v.y, nC.y) : -INF;                  \
                e.z = sC1 ? min3f(m1P2v.z, m1P1v.z, nC.z) : -INF;                  \
                e.w = sD1 ? min3f(m1P2v.w, m1P1v.w, nC.w) : -INF;                  \
                eT4[ETI][eWr1] = e;                                                \
            }                                                                      \
            m1P2v = m1P1v; m1P1v = nC;                                             \
        }                                                                          \
    } while (0)

    #define MAX9(ETI, xCv, ecv)                                                    \
    do {                                                                           \
        const float4* eP_ = eT4[ETI];                                              \
        float4 A0 = eP_[oRd],           B0 = eP_[oRd + 1];                         \
        float4 A1 = eP_[oRd + EW4],     B1 = eP_[oRd + EW4 + 1];                   \
        float4 A2 = eP_[oRd + 2 * EW4], B2 = eP_[oRd + 2 * EW4 + 1];               \
        float4 va, vb;                                                             \
        va.x = max3f(A0.x, A1.x, A2.x); va.y = max3f(A0.y, A1.y, A2.y);            \
        va.z = max3f(A0.z, A1.z, A2.z); va.w = max3f(A0.w, A1.w, A2.w);            \
        vb.x = max3f(B0.x, B1.x, B2.x); vb.y = max3f(B0.y, B1.y, B2.y);            \
        vb.z = max3f(B0.z, B1.z, B2.z);                                            \
        xCv.x = max3f(va.y, va.z, va.w); xCv.y = max3f(va.z, va.w, vb.x);          \
        xCv.z = max3f(va.w, vb.x, vb.y); xCv.w = max3f(vb.x, vb.y, vb.z);          \
        ecv.x = A1.z; ecv.y = A1.w; ecv.z = B1.x; ecv.w = B1.y;                    \
    } while (0)

    for (int k = 0; k < (TDZ + 4) / 2; ++k) {
        const int i0 = 2 * k, i1 = 2 * k + 1;
        const int slot0 = i0 & 3, slot1 = i1 & 3;

        // B1: pair slices loaded. k<3: only gloads outstanding -> full drain.
        // k>=3: leave prior pair's stores (4; 2 at step 20) in flight.
        if (k < 3) { BAR_FULL(); }
        else if (step == NUM_ITER) { BAR_VM2(); }
        else { BAR_VM4(); }

        // early skel prefetch (oldest VMEM of the pair)
        float4 ggPre0, ggPre1;
        if (step > 0 && i0 >= 4) { ggPre0 = sk4[ob]; ggPre1 = sk4[ob + HW4]; }
        __builtin_amdgcn_sched_barrier(0);

        // issue next pair (slices 2k+2, 2k+3) into the opposite slots
        if (k <= (TDZ + 4) / 2 - 2) {
            for (int s = 0; s < 2; ++s) {
                int z = z0 + 2 * k + s;          // slice 2k+2+s -> z0-2+(2k+2+s)
                bool zok = (unsigned)z < D_DIM;
                const float* p = in + (size_t)z * HW;
                const float* s0 = (zok && lVal0) ? (p + lOff0) : infp;
                GLOAD_LDS(s0, &aS4[(i0 + 2 + s) & 3][wbase]);
                if (hasL1) {
                    const float* s1 = (zok && lVal1) ? (p + lOff1) : infp;
                    GLOAD_LDS(s1, &aS4[(i0 + 2 + s) & 3][256 + wbase]);
                }
            }
        }
        __builtin_amdgcn_sched_barrier(0);

        const bool zp0 = (unsigned)(z0 - 3 + i0) < D_DIM;
        const bool zp1 = (unsigned)(z0 - 3 + i1) < D_DIM;
        const bool doE = (i0 >= 2);

        // ---- erode both slices -> eT4[0], eT4[1] ----
        ERODE_SLICE(slot0, zp0, doE, 0, m0P2, m0P1, m1P2, m1P1);
        ERODE_SLICE(slot1, zp1, (i1 >= 2), 1, m0P2, m0P1, m1P2, m1P1);

        // a-centers for both slices (issued pre-B2; aS4 pair stable)
        const float4 aCn0 = aS4[slot0][oAc];
        const float4 aCn1 = aS4[slot1][oAc];

        BAR_LDS();  // B2: eT4 ready (vmcnt NOT drained — next pair in flight)

        // ---- out both slices ----
        {
            float4 xC0, ecB0, xC1, ecB1;
            if (doE && zp0) { MAX9(0, xC0, ecB0); } else { xC0 = ninf4; ecB0 = ninf4; }
            if (doE && zp1) { MAX9(1, xC1, ecB1); } else { xC1 = ninf4; ecB1 = ninf4; }

            if (i0 >= 4) {
                // output slice i0 (z = z0-4+i0)
                {
                    float4 dl;
                    dl.x = leaky(acP2.x - max3f(xP2.x, xP1.x, xC0.x));
                    dl.y = leaky(acP2.y - max3f(xP2.y, xP1.y, xC0.y));
                    dl.z = leaky(acP2.z - max3f(xP2.z, xP1.z, xC0.z));
                    dl.w = leaky(acP2.w - max3f(xP2.w, xP1.w, xC0.w));
                    if (step < NUM_ITER) aout4[ob] = ecP;
                    if (step == 0) {
                        sk4[ob] = dl;
                    } else {
                        float4 gg = ggPre0, up, gn;
                        up.x = leaky(dl.x - gg.x * dl.x); gn.x = gg.x + up.x;
                        up.y = leaky(dl.y - gg.y * dl.y); gn.y = gg.y + up.y;
                        up.z = leaky(dl.z - gg.z * dl.z); gn.z = gg.z + up.z;
                        up.w = leaky(dl.w - gg.w * dl.w); gn.w = gg.w + up.w;
                        sk4[ob] = gn;
                        if (step == 1)
                            lsum += fabsf(gn.x) + fabsf(gn.y) + fabsf(gn.z) + fabsf(gn.w);
                        else
                            lsum += fabsf(up.x) + fabsf(up.y) + fabsf(up.z) + fabsf(up.w);
                    }
                }
                // output slice i1 (z = z0-4+i1)
                {
                    float4 dl;
                    dl.x = leaky(acP1.x - max3f(xP1.x, xC0.x, xC1.x));
                    dl.y = leaky(acP1.y - max3f(xP1.y, xC0.y, xC1.y));
                    dl.z = leaky(acP1.z - max3f(xP1.z, xC0.z, xC1.z));
                    dl.w = leaky(acP1.w - max3f(xP1.w, xC0.w, xC1.w));
                    if (step < NUM_ITER) aout4[ob + HW4] = ecB0;
                    if (step == 0) {
                        sk4[ob + HW4] = dl;
                    } else {
                        float4 gg = ggPre1, up, gn;
                        up.x = leaky(dl.x - gg.x * dl.x); gn.x = gg.x + up.x;
                        up.y = leaky(dl.y - gg.y * dl.y); gn.y = gg.y + up.y;
                        up.z = leaky(dl.z - gg.z * dl.z); gn.z = gg.z + up.z;
                        up.w = leaky(dl.w - gg.w * dl.w); gn.w = gg.w + up.w;
                        sk4[ob + HW4] = gn;
                        if (step == 1)
                            lsum += fabsf(gn.x) + fabsf(gn.y) + fabsf(gn.z) + fabsf(gn.w);
                        else
                            lsum += fabsf(up.x) + fabsf(up.y) + fabsf(up.z) + fabsf(up.w);
                    }
                }
                ob += 2 * HW4;
            }
            xP2 = xC0; xP1 = xC1;
            acP2 = aCn0; acP1 = aCn1;
            ecP = ecB1;
        }
    }

    #undef ERODE_SLICE
    #undef MAX9

    // dn reduction: one double atomic per block
    if (step > 0) {
        #pragma unroll
        for (int off = 32; off > 0; off >>= 1)
            lsum += __shfl_down(lsum, off, 64);
        const int lane = t & 63, wid = t >> 6;
        if (lane == 0) wsum[wid] = lsum;
        __syncthreads();
        if (t == 0) {
            float b = wsum[0] + wsum[1] + wsum[2] + wsum[3];
            atomicAdd(&slots[step], (double)b);
        }
    }
}

extern "C" void kernel_launch(void* const* d_in, const int* in_sizes, int n_in,
                              void* d_out, int out_size, void* d_ws, size_t ws_size,
                              hipStream_t stream) {
    const float* img = (const float*)d_in[0];
    float* out = (float*)d_out;
    float* buf0 = (float*)d_ws;
    float* buf1 = buf0 + NTOT;
    double* slots = (double*)(buf1 + NTOT);

    init_slots<<<1, 64, 0, stream>>>(slots);

    dim3 grid(W_DIM / TW, H_DIM / TH, (D_DIM / TDZ) * NIMG);
    for (int s = 0; s <= NUM_ITER; ++s) {
        const float* ain = (s == 0) ? img : ((s & 1) ? buf0 : buf1);
        float* aout = (s & 1) ? buf1 : buf0;
        skel_step<<<grid, 256, 0, stream>>>(ain, aout, out, slots, s);
    }
}

// Round 16
// 336.287 us; speedup vs baseline: 1.2877x; 1.1401x over previous
//
#include <hip/hip_runtime.h>
#include <math.h>

#define D_DIM 128
#define H_DIM 256
#define W_DIM 256
#define HW (H_DIM * W_DIM)
#define HW4 (HW / 4)
#define NIMG 2
#define NPI (D_DIM * HW)
#define NTOT (NIMG * NPI)

#define TDZ 16
#define TH 16
#define TW 64

#define AW4R 18  // real aS chunks/row: chunk c -> gx = x0-4+4c (x0-4 .. x0+67)
#define AW4 19   // padded aS row stride
#define AH 20    // aS rows: gy = y0-2 .. y0+17
#define EW4R 17  // real eT chunks/row: chunk c -> gx = x0-2+4c (x0-2 .. x0+65)
#define EW4 19   // padded eT row stride
#define EH 18    // eT rows: gy = y0-1 .. y0+16

#define NLOADLIN (AH * AW4)   // 380 padded-linear load slots
#define NLOADP 384            // rounded to 6 full waves
#define NERO  (EH * EW4R)     // 306 real erode items
#define NOUT  (TH * (TW/4))   // 256

#define NUM_ITER 20
#define STOP_THRESH 1e-4

__device__ __forceinline__ float min3f(float a, float b, float c) { return fminf(fminf(a, b), c); }
__device__ __forceinline__ float max3f(float a, float b, float c) { return fmaxf(fmaxf(a, b), c); }
__device__ __forceinline__ float leaky(float x) { return fmaxf(x, 0.01f * x); }

// lane L receives lane L+1's value within each 16-lane DPP row (row_shl:1).
// Must be executed by ALL lanes (uniform control flow) so source data exists.
__device__ __forceinline__ float dpp_shl1(float v) {
    int i = __float_as_int(v);
    int r = __builtin_amdgcn_update_dpp(i, i, 0x101, 0xF, 0xF, false);
    return __int_as_float(r);
}

// B1 variants: drain gloads but leave prior-pair stores in flight where safe.
#define BAR_FULL() do { asm volatile("s_waitcnt vmcnt(0) lgkmcnt(0)" ::: "memory"); \
                        __builtin_amdgcn_s_barrier(); \
                        __builtin_amdgcn_sched_barrier(0); } while (0)
#define BAR_VM4()  do { asm volatile("s_waitcnt vmcnt(4) lgkmcnt(0)" ::: "memory"); \
                        __builtin_amdgcn_s_barrier(); \
                        __builtin_amdgcn_sched_barrier(0); } while (0)
#define BAR_VM2()  do { asm volatile("s_waitcnt vmcnt(2) lgkmcnt(0)" ::: "memory"); \
                        __builtin_amdgcn_s_barrier(); \
                        __builtin_amdgcn_sched_barrier(0); } while (0)
// B2: LDS-only drain — keeps global_load_lds for the next pair in flight
#define BAR_LDS() do { asm volatile("s_waitcnt lgkmcnt(0)" ::: "memory"); \
                       __builtin_amdgcn_s_barrier(); \
                       __builtin_amdgcn_sched_barrier(0); } while (0)

#define GLOAD_LDS(gp, lp) \
    __builtin_amdgcn_global_load_lds((const __attribute__((address_space(1))) unsigned int*)(gp), \
                                     (__attribute__((address_space(3))) unsigned int*)(lp), 16, 0, 0)

__global__ void init_slots(double* slots) {
    int t = threadIdx.x;
    if (t < 32) slots[t] = 0.0;
    if (t >= 32 && t < 36) ((float*)(slots + 32))[t - 32] = INFINITY;  // 16B +INF cell
}

// R15 (pair-unrolled) + DPP sliding-window dilation: out phase reads only its
// own eT column (3 b128) and gets the neighbor column's vertical max via
// row_shl:1 DPP (VALU, no LDS). Boundary lanes (wq==15) read the 17th column.
__global__ __launch_bounds__(256) void skel_step(
    const float* __restrict__ a_in,
    float* __restrict__ a_out,
    float* __restrict__ skel,
    double* __restrict__ slots,
    int step)
{
    __shared__ float4 aS4[4][NLOADP];  // 24576 B (4 slice slots, gload dest)
    __shared__ float4 eT4[2][EH * EW4];// 10944 B (padded rows)
    __shared__ float wsum[4];
    __shared__ int s_active;

    const int t = threadIdx.x;

    if (t == 0) {
        int act = 1;
        for (int j = 1; j < step; ++j)
            if (!(slots[j] >= STOP_THRESH * (double)NTOT)) { act = 0; break; }
        s_active = act;
    }
    __syncthreads();
    if (!s_active) return;

    const float* infp = (const float*)(slots + 32);

    // XCD-aware swizzle: grid (4,16,16) = 1024 blocks; XCD k owns swz in
    // [128k,128(k+1)) = full xy coverage of 2 adjacent z-slabs.
    const int lid = blockIdx.x + 4 * (blockIdx.y + 16 * blockIdx.z);
    const int swz = (lid & 7) * 128 + (lid >> 3);
    const int bx = swz & 3;
    const int by = (swz >> 2) & 15;
    const int zz = swz >> 6;           // 0..15
    const int bz = zz & 7, img = zz >> 3;
    const int x0 = bx * TW, y0 = by * TH, z0 = bz * TDZ;

    const float* in = a_in + (size_t)img * NPI;
    float4* aout4 = (float4*)(a_out + (size_t)img * NPI);
    float4* sk4 = (float4*)(skel + (size_t)img * NPI);

    // ---- load items in PADDED-linear order: q0 = t, q1 = t+256 (t<128) ----
    int lOff0; bool lVal0;
    {
        int lr = t / AW4, lc = t - lr * AW4;
        int gy = y0 - 2 + lr, gx = x0 - 4 + 4 * lc;
        lVal0 = (lc < AW4R) && ((unsigned)gy < H_DIM) && ((unsigned)gx <= (unsigned)(W_DIM - 4));
        lOff0 = gy * W_DIM + gx;
    }
    const bool hasL1 = t < 128;          // wave-uniform
    int lOff1 = 0; bool lVal1 = false;
    if (hasL1) {
        int q = t + 256;
        int lr = q / AW4, lc = q - lr * AW4;
        int gy = y0 - 2 + lr, gx = x0 - 4 + 4 * lc;
        lVal1 = (q < NLOADLIN) && (lc < AW4R) && ((unsigned)gy < H_DIM)
                && ((unsigned)gx <= (unsigned)(W_DIM - 4));
        lOff1 = gy * W_DIM + gx;
    }
    const int wbase = (t >> 6) << 6;     // wave-uniform LDS base (element units)

    // ---- erode items (real 17-wide grid; padded stride-19 addressing) ----
    int eRd0, eWr0; bool sA0, sB0, sC0, sD0;
    {
        int mh = t / EW4R, ej = t - mh * EW4R;
        eRd0 = mh * AW4 + ej;
        eWr0 = mh * EW4 + ej;
        int gy = y0 - 1 + mh;
        bool gok = (unsigned)gy < H_DIM;
        int gxb = x0 - 2 + 4 * ej;
        sA0 = gok && ((unsigned)(gxb + 0) < W_DIM);
        sB0 = gok && ((unsigned)(gxb + 1) < W_DIM);
        sC0 = gok && ((unsigned)(gxb + 2) < W_DIM);
        sD0 = gok && ((unsigned)(gxb + 3) < W_DIM);
    }
    const bool hasE1 = t < (NERO - 256);    // t < 50
    int eRd1 = 0, eWr1 = 0; bool sA1 = false, sB1 = false, sC1 = false, sD1 = false;
    if (hasE1) {
        int q = t + 256;
        int mh = q / EW4R, ej = q - mh * EW4R;
        eRd1 = mh * AW4 + ej;
        eWr1 = mh * EW4 + ej;
        int gy = y0 - 1 + mh;
        bool gok = (unsigned)gy < H_DIM;
        int gxb = x0 - 2 + 4 * ej;
        sA1 = gok && ((unsigned)(gxb + 0) < W_DIM);
        sB1 = gok && ((unsigned)(gxb + 1) < W_DIM);
        sC1 = gok && ((unsigned)(gxb + 2) < W_DIM);
        sD1 = gok && ((unsigned)(gxb + 3) < W_DIM);
    }

    // ---- out item ----
    const int oh = t >> 4, wq = t & 15;
    const bool isB = (wq == 15);         // boundary lane: owns the 17th column
    const int oRd = oh * EW4 + wq;
    const int oAc = (oh + 2) * AW4 + wq + 1;
    size_t ob = ((size_t)z0 * HW + (size_t)(y0 + oh) * W_DIM + (size_t)x0) / 4 + wq;

    const float INF = INFINITY;
    const float4 ninf4 = make_float4(-INF, -INF, -INF, -INF);
    const float4 inf4 = make_float4(INF, INF, INF, INF);
    // rolling chains (advance by 2 per pair)
    float4 m0P2 = inf4, m0P1 = inf4, m1P2 = inf4, m1P1 = inf4;
    float4 xP2 = ninf4, xP1 = ninf4;
    float4 acP2 = make_float4(0, 0, 0, 0), acP1 = acP2, ecP = acP2;
    float lsum = 0.f;

    // ---- prologue: issue slices 0,1 into slots 0,1 ----
    for (int s = 0; s < 2; ++s) {
        int z = z0 - 2 + s;
        bool zok = (unsigned)z < D_DIM;
        const float* p = in + (size_t)z * HW;
        const float* s0 = (zok && lVal0) ? (p + lOff0) : infp;
        GLOAD_LDS(s0, &aS4[s][wbase]);
        if (hasL1) {
            const float* s1 = (zok && lVal1) ? (p + lOff1) : infp;
            GLOAD_LDS(s1, &aS4[s][256 + wbase]);
        }
    }

    #define ERODE_SLICE(SLOT, ZPV, DO_E, ETI, mP2v, mP1v, m1P2v, m1P1v)            \
    do {                                                                           \
        const float4* s_ = aS4[SLOT];                                              \
        float4 a0 = s_[eRd0],           b0 = s_[eRd0 + 1];                         \
        float4 a1 = s_[eRd0 + AW4],     b1 = s_[eRd0 + AW4 + 1];                   \
        float4 a2 = s_[eRd0 + 2 * AW4], b2 = s_[eRd0 + 2 * AW4 + 1];               \
        float4 va, vb, mC;                                                         \
        va.x = min3f(a0.x, a1.x, a2.x); va.y = min3f(a0.y, a1.y, a2.y);            \
        va.z = min3f(a0.z, a1.z, a2.z); va.w = min3f(a0.w, a1.w, a2.w);            \
        vb.x = min3f(b0.x, b1.x, b2.x); vb.y = min3f(b0.y, b1.y, b2.y);            \
        vb.z = min3f(b0.z, b1.z, b2.z);                                            \
        mC.x = min3f(va.y, va.z, va.w); mC.y = min3f(va.z, va.w, vb.x);            \
        mC.z = min3f(va.w, vb.x, vb.y); mC.w = min3f(vb.x, vb.y, vb.z);            \
        if ((DO_E) && (ZPV)) {                                                     \
            float4 e;                                                              \
            e.x = sA0 ? min3f(mP2v.x, mP1v.x, mC.x) : -INF;                        \
            e.y = sB0 ? min3f(mP2v.y, mP1v.y, mC.y) : -INF;                        \
            e.z = sC0 ? min3f(mP2v.z, mP1v.z, mC.z) : -INF;                        \
            e.w = sD0 ? min3f(mP2v.w, mP1v.w, mC.w) : -INF;                        \
            eT4[ETI][eWr0] = e;                                                    \
        }                                                                          \
        mP2v = mP1v; mP1v = mC;                                                    \
        if (hasE1) {                                                               \
            float4 c0 = s_[eRd1],           d0 = s_[eRd1 + 1];                     \
            float4 c1 = s_[eRd1 + AW4],     d1 = s_[eRd1 + AW4 + 1];               \
            float4 c2 = s_[eRd1 + 2 * AW4], d2 = s_[eRd1 + 2 * AW4 + 1];           \
            float4 wa, wb, nC;                                                     \
            wa.x = min3f(c0.x, c1.x, c2.x); wa.y = min3f(c0.y, c1.y, c2.y);        \
            wa.z = min3f(c0.z, c1.z, c2.z); wa.w = min3f(c0.w, c1.w, c2.w);        \
            wb.x = min3f(d0.x, d1.x, d2.x); wb.y = min3f(d0.y, d1.y, d2.y);        \
            wb.z = min3f(d0.z, d1.z, d2.z);                                        \
            nC.x = min3f(wa.y, wa.z, wa.w); nC.y = min3f(wa.z, wa.w, wb.x);        \
            nC.z = min3f(wa.w, wb.x, wb.y); nC.w = min3f(wb.x, wb.y, wb.z);        \
            if ((DO_E) && (ZPV)) {                                                 \
                float4 e;                                                          \
                e.x = sA1 ? min3f(m1P2v.x, m1P1v.x, nC.x) : -INF;                  \
                e.y = sB1 ? min3f(m1P2v.y, m1P1v.y, nC.y) : -INF;                  \
                e.z = sC1 ? min3f(m1P2v.z, m1P1v.z, nC.z) : -INF;                  \
                e.w = sD1 ? min3f(m1P2v.w, m1P1v.w, nC.w) : -INF;                  \
                eT4[ETI][eWr1] = e;                                                \
            }                                                                      \
            m1P2v = m1P1v; m1P1v = nC;                                             \
        }                                                                          \
    } while (0)

    // DPP dilation: 3 own-column reads + divergent 17th-column reads on wq==15;
    // neighbor column's vertical max + raw center row via row_shl:1 DPP.
    // NOTE: dpp_shl1 must run in uniform control flow (all 256 lanes).
    #define MAX9(ETI, xCv, ecv)                                                    \
    do {                                                                           \
        const float4* eP_ = eT4[ETI];                                              \
        float4 A0 = eP_[oRd], A1 = eP_[oRd + EW4], A2 = eP_[oRd + 2 * EW4];        \
        float4 B0, B1, B2;                                                         \
        if (isB) {                                                                 \
            B0 = eP_[oRd + 1]; B1 = eP_[oRd + EW4 + 1]; B2 = eP_[oRd + 2 * EW4 + 1]; \
        }                                                                          \
        float4 vm;                                                                 \
        vm.x = max3f(A0.x, A1.x, A2.x); vm.y = max3f(A0.y, A1.y, A2.y);            \
        vm.z = max3f(A0.z, A1.z, A2.z); vm.w = max3f(A0.w, A1.w, A2.w);            \
        float sx = dpp_shl1(vm.x), sy = dpp_shl1(vm.y), sz = dpp_shl1(vm.z);       \
        float c1x = dpp_shl1(A1.x), c1y = dpp_shl1(A1.y);                          \
        float bvx = max3f(B0.x, B1.x, B2.x);                                       \
        float bvy = max3f(B0.y, B1.y, B2.y);                                       \
        float bvz = max3f(B0.z, B1.z, B2.z);                                       \
        float nbx = isB ? bvx : sx;                                                \
        float nby = isB ? bvy : sy;                                                \
        float nbz = isB ? bvz : sz;                                                \
        xCv.x = max3f(vm.y, vm.z, vm.w);                                           \
        xCv.y = max3f(vm.z, vm.w, nbx);                                            \
        xCv.z = max3f(vm.w, nbx, nby);                                             \
        xCv.w = max3f(nbx, nby, nbz);                                              \
        ecv.x = A1.z; ecv.y = A1.w;                                                \
        ecv.z = isB ? B1.x : c1x;                                                  \
        ecv.w = isB ? B1.y : c1y;                                                  \
    } while (0)

    for (int k = 0; k < (TDZ + 4) / 2; ++k) {
        const int i0 = 2 * k, i1 = 2 * k + 1;
        const int slot0 = i0 & 3, slot1 = i1 & 3;

        // B1: pair slices loaded. k<3: only gloads outstanding -> full drain.
        // k>=3: leave prior pair's stores (4; 2 at step 20) in flight.
        if (k < 3) { BAR_FULL(); }
        else if (step == NUM_ITER) { BAR_VM2(); }
        else { BAR_VM4(); }

        // early skel prefetch (oldest VMEM of the pair)
        float4 ggPre0, ggPre1;
        if (step > 0 && i0 >= 4) { ggPre0 = sk4[ob]; ggPre1 = sk4[ob + HW4]; }
        __builtin_amdgcn_sched_barrier(0);

        // issue next pair (slices 2k+2, 2k+3) into the opposite slots
        if (k <= (TDZ + 4) / 2 - 2) {
            for (int s = 0; s < 2; ++s) {
                int z = z0 + 2 * k + s;          // slice 2k+2+s -> z0-2+(2k+2+s)
                bool zok = (unsigned)z < D_DIM;
                const float* p = in + (size_t)z * HW;
                const float* s0 = (zok && lVal0) ? (p + lOff0) : infp;
                GLOAD_LDS(s0, &aS4[(i0 + 2 + s) & 3][wbase]);
                if (hasL1) {
                    const float* s1 = (zok && lVal1) ? (p + lOff1) : infp;
                    GLOAD_LDS(s1, &aS4[(i0 + 2 + s) & 3][256 + wbase]);
                }
            }
        }
        __builtin_amdgcn_sched_barrier(0);

        const bool zp0 = (unsigned)(z0 - 3 + i0) < D_DIM;
        const bool zp1 = (unsigned)(z0 - 3 + i1) < D_DIM;
        const bool doE = (i0 >= 2);

        // ---- erode both slices -> eT4[0], eT4[1] ----
        ERODE_SLICE(slot0, zp0, doE, 0, m0P2, m0P1, m1P2, m1P1);
        ERODE_SLICE(slot1, zp1, (i1 >= 2), 1, m0P2, m0P1, m1P2, m1P1);

        // a-centers for both slices (issued pre-B2; aS4 pair stable)
        const float4 aCn0 = aS4[slot0][oAc];
        const float4 aCn1 = aS4[slot1][oAc];

        BAR_LDS();  // B2: eT4 ready (vmcnt NOT drained — next pair in flight)

        // ---- out both slices ----
        {
            float4 xC0, ecB0, xC1, ecB1;
            if (doE && zp0) { MAX9(0, xC0, ecB0); } else { xC0 = ninf4; ecB0 = ninf4; }
            if (doE && zp1) { MAX9(1, xC1, ecB1); } else { xC1 = ninf4; ecB1 = ninf4; }

            if (i0 >= 4) {
                // output slice i0 (z = z0-4+i0)
                {
                    float4 dl;
                    dl.x = leaky(acP2.x - max3f(xP2.x, xP1.x, xC0.x));
                    dl.y = leaky(acP2.y - max3f(xP2.y, xP1.y, xC0.y));
                    dl.z = leaky(acP2.z - max3f(xP2.z, xP1.z, xC0.z));
                    dl.w = leaky(acP2.w - max3f(xP2.w, xP1.w, xC0.w));
                    if (step < NUM_ITER) aout4[ob] = ecP;
                    if (step == 0) {
                        sk4[ob] = dl;
                    } else {
                        float4 gg = ggPre0, up, gn;
                        up.x = leaky(dl.x - gg.x * dl.x); gn.x = gg.x + up.x;
                        up.y = leaky(dl.y - gg.y * dl.y); gn.y = gg.y + up.y;
                        up.z = leaky(dl.z - gg.z * dl.z); gn.z = gg.z + up.z;
                        up.w = leaky(dl.w - gg.w * dl.w); gn.w = gg.w + up.w;
                        sk4[ob] = gn;
                        if (step == 1)
                            lsum += fabsf(gn.x) + fabsf(gn.y) + fabsf(gn.z) + fabsf(gn.w);
                        else
                            lsum += fabsf(up.x) + fabsf(up.y) + fabsf(up.z) + fabsf(up.w);
                    }
                }
                // output slice i1 (z = z0-4+i1)
                {
                    float4 dl;
                    dl.x = leaky(acP1.x - max3f(xP1.x, xC0.x, xC1.x));
                    dl.y = leaky(acP1.y - max3f(xP1.y, xC0.y, xC1.y));
                    dl.z = leaky(acP1.z - max3f(xP1.z, xC0.z, xC1.z));
                    dl.w = leaky(acP1.w - max3f(xP1.w, xC0.w, xC1.w));
                    if (step < NUM_ITER) aout4[ob + HW4] = ecB0;
                    if (step == 0) {
                        sk4[ob + HW4] = dl;
                    } else {
                        float4 gg = ggPre1, up, gn;
                        up.x = leaky(dl.x - gg.x * dl.x); gn.x = gg.x + up.x;
                        up.y = leaky(dl.y - gg.y * dl.y); gn.y = gg.y + up.y;
                        up.z = leaky(dl.z - gg.z * dl.z); gn.z = gg.z + up.z;
                        up.w = leaky(dl.w - gg.w * dl.w); gn.w = gg.w + up.w;
                        sk4[ob + HW4] = gn;
                        if (step == 1)
                            lsum += fabsf(gn.x) + fabsf(gn.y) + fabsf(gn.z) + fabsf(gn.w);
                        else
                            lsum += fabsf(up.x) + fabsf(up.y) + fabsf(up.z) + fabsf(up.w);
                    }
                }
                ob += 2 * HW4;
            }
            xP2 = xC0; xP1 = xC1;
            acP2 = aCn0; acP1 = aCn1;
            ecP = ecB1;
        }
    }

    #undef ERODE_SLICE
    #undef MAX9

    // dn reduction: one double atomic per block
    if (step > 0) {
        #pragma unroll
        for (int off = 32; off > 0; off >>= 1)
            lsum += __shfl_down(lsum, off, 64);
        const int lane = t & 63, wid = t >> 6;
        if (lane == 0) wsum[wid] = lsum;
        __syncthreads();
        if (t == 0) {
            float b = wsum[0] + wsum[1] + wsum[2] + wsum[3];
            atomicAdd(&slots[step], (double)b);
        }
    }
}

extern "C" void kernel_launch(void* const* d_in, const int* in_sizes, int n_in,
                              void* d_out, int out_size, void* d_ws, size_t ws_size,
                              hipStream_t stream) {
    const float* img = (const float*)d_in[0];
    float* out = (float*)d_out;
    float* buf0 = (float*)d_ws;
    float* buf1 = buf0 + NTOT;
    double* slots = (double*)(buf1 + NTOT);

    init_slots<<<1, 64, 0, stream>>>(slots);

    dim3 grid(W_DIM / TW, H_DIM / TH, (D_DIM / TDZ) * NIMG);
    for (int s = 0; s <= NUM_ITER; ++s) {
        const float* ain = (s == 0) ? img : ((s & 1) ? buf0 : buf1);
        float* aout = (s & 1) ? buf1 : buf0;
        skel_step<<<grid, 256, 0, stream>>>(ain, aout, out, slots, s);
    }
}